// Round 9
// baseline (540.400 us; speedup 1.0000x reference)
//
#include <hip/hip_runtime.h>

#define NNODES 100000
#define NEDGES 1600000
#define EPSV 1e-5f

#define NB   391      // buckets of 256 consecutive dst nodes: ceil(100000/256)
#define BCAP 4608     // bucket capacity; mean 4092, sigma ~64 -> 8-sigma margin
#define EPB  4096     // edges per partition workgroup

typedef __attribute__((ext_vector_type(8))) short bf16x8;
typedef __attribute__((ext_vector_type(4))) float f32x4;
typedef __attribute__((ext_vector_type(2))) float f32x2;

#if defined(__has_builtin)
#  if __has_builtin(__builtin_amdgcn_cvt_pk_f32_fp8) && __has_builtin(__builtin_amdgcn_cvt_pk_fp8_f32)
#    define HAS_FP8_CVT 1
#  endif
#endif
#ifndef HAS_FP8_CVT
#  define HAS_FP8_CVT 0
#endif

// ----------------------------------------------------------- bf16 helpers ---
__device__ __forceinline__ ushort f2bf(float f) {
    union { float f; uint u; } c; c.f = f;
    uint u = c.u;
    return (ushort)((u + 0x7fffu + ((u >> 16) & 1u)) >> 16);
}
__device__ __forceinline__ uint pack2(float f0, float f1) {
    return (uint)f2bf(f0) | ((uint)f2bf(f1) << 16);
}

// ------------------------------------------------------------ fp8 helpers ---
// OCP e4m3fn. HW path: v_cvt_pk_{f32_fp8,fp8_f32}. Manual fallback: FTZ+sat.
#if !HAS_FP8_CVT
__device__ __forceinline__ float fp8_dec1(uint b) {
    uint e = (b >> 3) & 0xFu, m = b & 7u, s = b >> 7;
    union { uint u; float f; } c;
    c.u = e ? ((s << 31) | ((e + 120u) << 23) | (m << 20)) : (s << 31);
    return c.f;
}
__device__ __forceinline__ uint fp8_enc1(float x) {
    union { float f; uint u; } c; c.f = x;
    uint u = c.u, s = u >> 31;
    float ax = fabsf(x);
    if (ax < 0.015625f) return s << 7;        // FTZ below 2^-6
    if (ax > 448.0f)    return (s << 7) | 0x7Eu;
    u = u + 0x7FFFFu + ((u >> 20) & 1u);      // RNE at bit 20
    uint e = ((u >> 23) & 0xFFu) - 120u;
    uint m = (u >> 20) & 7u;
    if (e > 15u) return (s << 7) | 0x7Eu;
    return (s << 7) | (e << 3) | m;
}
#endif

// decode 8 fp8 from uint2, packed-accumulate into 4 f32x2 (v_pk_add_f32)
__device__ __forceinline__ void accf8p(f32x2* a, uint2 v) {
#if HAS_FP8_CVT
    a[0] += __builtin_amdgcn_cvt_pk_f32_fp8((int)v.x, false);
    a[1] += __builtin_amdgcn_cvt_pk_f32_fp8((int)v.x, true);
    a[2] += __builtin_amdgcn_cvt_pk_f32_fp8((int)v.y, false);
    a[3] += __builtin_amdgcn_cvt_pk_f32_fp8((int)v.y, true);
#else
    a[0] += (f32x2){fp8_dec1(v.x & 0xFFu), fp8_dec1((v.x >> 8) & 0xFFu)};
    a[1] += (f32x2){fp8_dec1((v.x >> 16) & 0xFFu), fp8_dec1(v.x >> 24)};
    a[2] += (f32x2){fp8_dec1(v.y & 0xFFu), fp8_dec1((v.y >> 8) & 0xFFu)};
    a[3] += (f32x2){fp8_dec1((v.y >> 16) & 0xFFu), fp8_dec1(v.y >> 24)};
#endif
}

__device__ __forceinline__ uint f2fp8(float f) {
#if HAS_FP8_CVT
    return ((uint)__builtin_amdgcn_cvt_pk_fp8_f32(f, f, 0, false)) & 0xFFu;
#else
    return fp8_enc1(f);
#endif
}

__device__ __forceinline__ uint packf8_4(float f0, float f1, float f2, float f3) {
#if HAS_FP8_CVT
    int r = 0;
    r = __builtin_amdgcn_cvt_pk_fp8_f32(f0, f1, r, false);
    r = __builtin_amdgcn_cvt_pk_fp8_f32(f2, f3, r, true);
    return (uint)r;
#else
    return fp8_enc1(f0) | (fp8_enc1(f1) << 8) | (fp8_enc1(f2) << 16) | (fp8_enc1(f3) << 24);
#endif
}

// --------------------------------------------------- async global->LDS ------
__device__ __forceinline__ void load_lds16(const ushort* g, ushort* l) {
    __builtin_amdgcn_global_load_lds(
        (const __attribute__((address_space(1))) void*)g,
        (__attribute__((address_space(3))) void*)l,
        16, 0, 0);
}

// ------------------------------------------------- CSR build, bucketed ------
__global__ __launch_bounds__(256) void part_kernel(
    const int* __restrict__ src, const int* __restrict__ dst,
    int* __restrict__ cursor, uint2* __restrict__ pairs, int E)
{
    __shared__ int lcnt[NB];
    __shared__ int lbase[NB];
    const int t = threadIdx.x;
    for (int i = t; i < NB; i += 256) lcnt[i] = 0;
    __syncthreads();

    const int base = blockIdx.x * EPB;
    const int lim  = min(base + EPB, E);

    for (int e = base + t; e < lim; e += 256)
        atomicAdd(&lcnt[((unsigned)dst[e]) >> 8], 1);
    __syncthreads();

    for (int i = t; i < NB; i += 256) {
        int c = lcnt[i];
        lbase[i] = c ? atomicAdd(&cursor[i], c) : 0;
        lcnt[i] = 0;
    }
    __syncthreads();

    for (int e = base + t; e < lim; e += 256) {
        int d = dst[e];
        int b = ((unsigned)d) >> 8;
        int p = lbase[b] + atomicAdd(&lcnt[b], 1);
        if (p < BCAP) pairs[(size_t)b * BCAP + p] = make_uint2((uint)src[e], (uint)d);
    }
}

__global__ __launch_bounds__(512) void bscan_kernel(const int* __restrict__ cursor,
                                                    int* __restrict__ colBase)
{
    __shared__ int s[512];
    int t = threadIdx.x;
    int v = (t < NB) ? min(cursor[t], BCAP) : 0;
    s[t] = v;
    __syncthreads();
    #pragma unroll
    for (int off = 1; off < 512; off <<= 1) {
        int a = (t >= off) ? s[t - off] : 0;
        __syncthreads();
        s[t] += a;
        __syncthreads();
    }
    if (t < NB) colBase[t] = s[t] - v;
}

__global__ __launch_bounds__(256) void csr_fin_kernel(
    const uint2* __restrict__ pairs, const int* __restrict__ cursor,
    const int* __restrict__ colBase, uint2* __restrict__ meta,
    int* __restrict__ col, int n)
{
    __shared__ int lcnt[256];
    __shared__ int lofs[256];
    const int b = blockIdx.x;
    const int t = threadIdx.x;
    const int ecnt  = min(cursor[b], BCAP);
    const int cbase = colBase[b];
    const uint2* __restrict__ pp = pairs + (size_t)b * BCAP;

    lcnt[t] = 0;
    __syncthreads();
    for (int e = t; e < ecnt; e += 256)
        atomicAdd(&lcnt[pp[e].y & 255u], 1);
    __syncthreads();

    const int v = lcnt[t];
    lofs[t] = v;
    __syncthreads();
    #pragma unroll
    for (int off = 1; off < 256; off <<= 1) {
        int a = (t >= off) ? lofs[t - off] : 0;
        __syncthreads();
        lofs[t] += a;
        __syncthreads();
    }
    const int excl = lofs[t] - v;

    const int node = (b << 8) + t;
    if (node < n)
        meta[node] = make_uint2((uint)(cbase + excl), (uint)v);   // (beg, cnt)
    __syncthreads();
    lcnt[t] = excl;                      // reuse as cursor
    __syncthreads();

    for (int e = t; e < ecnt; e += 256) {
        uint2 pr = pp[e];
        int p = cbase + atomicAdd(&lcnt[pr.y & 255u], 1);
        col[p] = (int)pr.x;
    }
}

// ------------------------------------------------------------ conversions ---
// x fp32 -> xbf (bf16, GEMM self-term) + xf8 (fp8, SLICE-MAJOR for gather).
// Slice-major: out8[(b>>5)*(N*32) + node*32 + (b&31)] where b = byte in row.
__global__ void cvt_x_kernel(const float* __restrict__ in, ushort* __restrict__ outb,
                             unsigned char* __restrict__ out8, int n4) {
    int i = blockIdx.x * blockDim.x + threadIdx.x;
    if (i < n4) {
        float4 v = ((const float4*)in)[i];
        ushort4 o;
        o.x = f2bf(v.x); o.y = f2bf(v.y); o.z = f2bf(v.z); o.w = f2bf(v.w);
        ((ushort4*)outb)[i] = o;
        uint byte = 4u * (uint)i;            // byte offset in row-major fp8
        uint nd   = byte >> 7;               // node (row = 128 B)
        uint b    = byte & 127u;             // byte within row
        uint idx  = (b >> 5) * ((uint)NNODES * 8u) + nd * 8u + ((b & 31u) >> 2);
        ((uint*)out8)[idx] = packf8_4(v.x, v.y, v.z, v.w);
    }
}

// All six weight transposes (w[K][Nout] fp32 -> wt[Nout][K] bf16) in one launch.
__global__ void wT_all_kernel(
    const float* __restrict__ w1l, const float* __restrict__ w1r,
    const float* __restrict__ w2l, const float* __restrict__ w2r,
    const float* __restrict__ w3l, const float* __restrict__ w3r,
    ushort* __restrict__ t1l, ushort* __restrict__ t1r,
    ushort* __restrict__ t2l, ushort* __restrict__ t2r,
    ushort* __restrict__ t3l, ushort* __restrict__ t3r)
{
    int idx = blockIdx.x * blockDim.x + threadIdx.x;
    const float* w; ushort* wt; int K, Nout, i;
    if      (idx <  16384) { w = w1l; wt = t1l; K = 128; Nout = 128; i = idx; }
    else if (idx <  32768) { w = w1r; wt = t1r; K = 128; Nout = 128; i = idx - 16384; }
    else if (idx <  65536) { w = w2l; wt = t2l; K = 128; Nout = 256; i = idx - 32768; }
    else if (idx <  98304) { w = w2r; wt = t2r; K = 128; Nout = 256; i = idx - 65536; }
    else if (idx < 163840) { w = w3l; wt = t3l; K = 256; Nout = 256; i = idx - 98304; }
    else if (idx < 229376) { w = w3r; wt = t3r; K = 256; Nout = 256; i = idx - 163840; }
    else return;
    int k = i / Nout, n = i - k * Nout;
    wt[(size_t)n * K + k] = f2bf(w[i]);
}

// ---------------------------------------------------- gather (mean, sliced) -
// XCD-sliced: fp8 features stored slice-major, 32 B per slice; slice region
// = N*32 B = 3.2 MB -> fits one XCD's 4 MB L2. slice = blockIdx % NS aligns
// each slice with a fixed XCD (round-robin dispatch), so the random row
// reads become L2-resident after first touch. Feature slices are disjoint
// -> no partial-sum combine. 4 lanes/node/slice, 64 nodes/block.
template<int D>
__global__ __launch_bounds__(256) void gather_f8s(
    const unsigned char* __restrict__ x, const uint2* __restrict__ meta,
    const int* __restrict__ col, ushort* __restrict__ agg, int n)
{
    constexpr int NS  = D / 32;          // 4 (D=128) or 8 (D=256) slices
    constexpr int NPB = 64;              // nodes per block (256 threads / 4)
    const int s    = blockIdx.x % NS;
    const int nb   = blockIdx.x / NS;
    const int node = nb * NPB + (threadIdx.x >> 2);
    const int lane = threadIdx.x & 3;
    if (node >= n) return;

    const unsigned char* __restrict__ xs = x + (size_t)s * ((size_t)NNODES * 32);
    const uint boff = (uint)lane * 8u;

    const uint2 m  = meta[node];         // (beg, cnt)
    const int  c   = (int)m.y;
    int        e   = (int)m.x;
    const int  end = e + c;

    f32x2 a[4];
    #pragma unroll
    for (int i = 0; i < 4; ++i) a[i] = (f32x2)0.0f;

    for (; e + 7 < end; e += 8) {
        uint o0 = ((uint)col[e]     << 5) + boff;
        uint o1 = ((uint)col[e + 1] << 5) + boff;
        uint o2 = ((uint)col[e + 2] << 5) + boff;
        uint o3 = ((uint)col[e + 3] << 5) + boff;
        uint o4 = ((uint)col[e + 4] << 5) + boff;
        uint o5 = ((uint)col[e + 5] << 5) + boff;
        uint o6 = ((uint)col[e + 6] << 5) + boff;
        uint o7 = ((uint)col[e + 7] << 5) + boff;
        uint2 v0 = *(const uint2*)(xs + o0);
        uint2 v1 = *(const uint2*)(xs + o1);
        uint2 v2 = *(const uint2*)(xs + o2);
        uint2 v3 = *(const uint2*)(xs + o3);
        uint2 v4 = *(const uint2*)(xs + o4);
        uint2 v5 = *(const uint2*)(xs + o5);
        uint2 v6 = *(const uint2*)(xs + o6);
        uint2 v7 = *(const uint2*)(xs + o7);
        accf8p(a, v0); accf8p(a, v1); accf8p(a, v2); accf8p(a, v3);
        accf8p(a, v4); accf8p(a, v5); accf8p(a, v6); accf8p(a, v7);
    }
    for (; e + 1 < end; e += 2) {
        uint2 v0 = *(const uint2*)(xs + ((uint)col[e]     << 5) + boff);
        uint2 v1 = *(const uint2*)(xs + ((uint)col[e + 1] << 5) + boff);
        accf8p(a, v0); accf8p(a, v1);
    }
    if (e < end) {
        uint2 v = *(const uint2*)(xs + ((uint)col[e] << 5) + boff);
        accf8p(a, v);
    }

    const float inv = 1.0f / fmaxf((float)c, 1.0f);
    uint4 o;
    o.x = pack2(a[0][0] * inv, a[0][1] * inv);
    o.y = pack2(a[1][0] * inv, a[1][1] * inv);
    o.z = pack2(a[2][0] * inv, a[2][1] * inv);
    o.w = pack2(a[3][0] * inv, a[3][1] * inv);
    // agg row = D bf16 = D*2 B = D/8 uint4; slice s covers uint4s [s*4, s*4+4)
    ((uint4*)agg)[(size_t)node * (D / 8) + s * 4 + lane] = o;
}

// ---------------------------------------------- fused SAGE layer (MFMA) -----
// out = bn(relu( agg @ wl + xin @ wr + bias )); optional SLICE-MAJOR fp8
// copy for the next layer's gather.
//
// m97 structure: global_load_lds(16B) staging into LINEAR LDS, BK=64,
// XOR-swizzle (row&7) applied to the global SOURCE chunk at stage time and
// to the ds_read_b128 chunk at read time (rule #21: both-sides-or-neither).
template<int DIN, int DOUT, bool OUTF32, bool WRITE8>
__global__ __launch_bounds__(256) void mfma_layer(
    const ushort* __restrict__ xin, const ushort* __restrict__ agg,
    const ushort* __restrict__ wlT, const ushort* __restrict__ wrT,
    const float* __restrict__ bias, const float* __restrict__ gamma,
    const float* __restrict__ beta, const float* __restrict__ rmean,
    const float* __restrict__ rvar, void* __restrict__ outp,
    unsigned char* __restrict__ out8, int M)
{
    constexpr int BM = 128, BN = 128, BK = 64;
    constexpr int NBY = DOUT / BN;             // 1 or 2 (power of 2)
    __shared__ ushort As[BM * BK];             // 16 KB, linear + src-side swizzle
    __shared__ ushort Bs[BN * BK];             // 16 KB

    const int tid  = threadIdx.x;
    const int lane = tid & 63;
    const int wid  = tid >> 6;
    const int wm   = (wid & 1) * 64;
    const int wn   = (wid >> 1) * 64;
    const int lr   = lane & 15;
    const int quad = lane >> 4;

    const int row0 = (blockIdx.x / NBY) * BM;
    const int col0 = (blockIdx.x % NBY) * BN;

    f32x4 acc[4][4] = {};

    const int srow = tid >> 3;                       // + r*32 per round
    const int schk = (tid & 7) ^ (srow & 7);         // swizzled source chunk

    #pragma unroll
    for (int phase = 0; phase < 2; ++phase) {
        const ushort* __restrict__ A = phase ? xin : agg;
        const ushort* __restrict__ W = phase ? wrT : wlT;

        for (int k0 = 0; k0 < DIN; k0 += BK) {
            __syncthreads();   // previous iteration's LDS reads complete
            #pragma unroll
            for (int r = 0; r < 4; ++r) {
                const int row = srow + r * 32;
                int gra = row0 + row; gra = gra < M ? gra : M - 1;
                load_lds16(A + (size_t)gra * DIN + k0 + schk * 8,
                           &As[(r * 256 + tid) * 8]);
                load_lds16(W + (size_t)(col0 + row) * DIN + k0 + schk * 8,
                           &Bs[(r * 256 + tid) * 8]);
            }
            __syncthreads();   // compiler drains vmcnt(0) here -> tiles ready

            #pragma unroll
            for (int sub = 0; sub < 2; ++sub) {
                bf16x8 af[4], bf[4];
                #pragma unroll
                for (int t = 0; t < 4; ++t) {
                    const int ra = wm + t * 16 + lr;
                    const int rb = wn + t * 16 + lr;
                    const int ca = ((sub << 2) | quad) ^ (ra & 7);
                    const int cb = ((sub << 2) | quad) ^ (rb & 7);
                    af[t] = *(const bf16x8*)&As[ra * BK + ca * 8];
                    bf[t] = *(const bf16x8*)&Bs[rb * BK + cb * 8];
                }
                #pragma unroll
                for (int mt = 0; mt < 4; ++mt)
                    #pragma unroll
                    for (int nt = 0; nt < 4; ++nt)
                        acc[mt][nt] = __builtin_amdgcn_mfma_f32_16x16x32_bf16(
                            af[mt], bf[nt], acc[mt][nt], 0, 0, 0);
            }
        }
    }

    float bj[4], sj[4], mj[4], bej[4];
    #pragma unroll
    for (int nt = 0; nt < 4; ++nt) {
        int gc = col0 + wn + nt * 16 + lr;
        bj[nt]  = bias[gc];
        sj[nt]  = rsqrtf(rvar[gc] + EPSV) * gamma[gc];
        mj[nt]  = rmean[gc];
        bej[nt] = beta[gc];
    }
    #pragma unroll
    for (int mt = 0; mt < 4; ++mt) {
        #pragma unroll
        for (int r = 0; r < 4; ++r) {
            int grow = row0 + wm + mt * 16 + quad * 4 + r;
            if (grow < M) {
                #pragma unroll
                for (int nt = 0; nt < 4; ++nt) {
                    int gc = col0 + wn + nt * 16 + lr;
                    float h = acc[mt][nt][r] + bj[nt];
                    h = fmaxf(h, 0.0f);
                    h = (h - mj[nt]) * sj[nt] + bej[nt];
                    if (OUTF32) ((float*)outp)[(size_t)grow * DOUT + gc] = h;
                    else        ((ushort*)outp)[(size_t)grow * DOUT + gc] = f2bf(h);
                    if (WRITE8)
                        out8[(size_t)(gc >> 5) * ((size_t)NNODES * 32)
                             + (size_t)grow * 32 + (gc & 31)] =
                            (unsigned char)f2fp8(h);
                }
            }
        }
    }
}

// ------------------------------------------------------------------ launch --
extern "C" void kernel_launch(void* const* d_in, const int* in_sizes, int n_in,
                              void* d_out, int out_size, void* d_ws, size_t ws_size,
                              hipStream_t stream) {
    const int N = NNODES;
    const int E = NEDGES;

    const float* x   = (const float*)d_in[0];
    const int*   ei  = (const int*)d_in[1];
    const int*   src = ei;
    const int*   dst = ei + E;

    const float* w1l = (const float*)d_in[2];
    const float* w1r = (const float*)d_in[3];
    const float* b1  = (const float*)d_in[4];
    const float* g1  = (const float*)d_in[5];
    const float* be1 = (const float*)d_in[6];
    const float* m1  = (const float*)d_in[7];
    const float* v1  = (const float*)d_in[8];

    const float* w2l = (const float*)d_in[9];
    const float* w2r = (const float*)d_in[10];
    const float* b2  = (const float*)d_in[11];
    const float* g2  = (const float*)d_in[12];
    const float* be2 = (const float*)d_in[13];
    const float* m2  = (const float*)d_in[14];
    const float* v2  = (const float*)d_in[15];

    const float* w3l = (const float*)d_in[16];
    const float* w3r = (const float*)d_in[17];
    const float* b3  = (const float*)d_in[18];
    const float* g3  = (const float*)d_in[19];
    const float* be3 = (const float*)d_in[20];
    const float* m3  = (const float*)d_in[21];
    const float* v3  = (const float*)d_in[22];

    float* out = (float*)d_out;

    // ---- workspace layout (16B-aligned segments) ----
    // pairs region (14.41 MB) is dead after csr_fin -> reused for xf8 then h1f8.
    char*   wp      = (char*)d_ws;
    uint2*  meta    = (uint2*)wp;   wp += (size_t)N * sizeof(uint2);   // (beg,cnt)
    int*    cursor  = (int*)wp;     wp += 512 * sizeof(int);
    int*    colBase = (int*)wp;     wp += 512 * sizeof(int);
    int*    col     = (int*)wp;     wp += (size_t)E * sizeof(int);
    uint2*  pairs   = (uint2*)wp;   wp += (size_t)NB * BCAP * sizeof(uint2);
    ushort* xbf     = (ushort*)wp;  wp += (size_t)N * 128 * sizeof(ushort);
    ushort* h1      = (ushort*)wp;  wp += (size_t)N * 128 * sizeof(ushort);
    ushort* h2      = (ushort*)wp;  wp += (size_t)N * 256 * sizeof(ushort);
    ushort* aggb    = (ushort*)wp;  wp += (size_t)N * 256 * sizeof(ushort);
    unsigned char* h2f8 = (unsigned char*)wp; wp += (size_t)N * 256;
    ushort* w1lT    = (ushort*)wp;  wp += 128 * 128 * sizeof(ushort);
    ushort* w1rT    = (ushort*)wp;  wp += 128 * 128 * sizeof(ushort);
    ushort* w2lT    = (ushort*)wp;  wp += 256 * 128 * sizeof(ushort);
    ushort* w2rT    = (ushort*)wp;  wp += 256 * 128 * sizeof(ushort);
    ushort* w3lT    = (ushort*)wp;  wp += 256 * 256 * sizeof(ushort);
    ushort* w3rT    = (ushort*)wp;

    unsigned char* xf8  = (unsigned char*)pairs;   // 12.8 MB <= 14.41 MB
    unsigned char* h1f8 = (unsigned char*)pairs;   // after xf8 is dead

    const int T = 256;

    // ---- CSR build (bucketed) ----
    hipMemsetAsync(cursor, 0, 512 * sizeof(int), stream);
    part_kernel<<<(E + EPB - 1) / EPB, 256, 0, stream>>>(src, dst, cursor, pairs, E);
    bscan_kernel<<<1, 512, 0, stream>>>(cursor, colBase);
    csr_fin_kernel<<<NB, 256, 0, stream>>>(pairs, cursor, colBase, meta, col, N);

    // ---- conversions (xf8 write must follow csr_fin: aliases pairs) ----
    cvt_x_kernel<<<((N * 128 / 4) + T - 1) / T, T, 0, stream>>>(x, xbf, xf8, N * 128 / 4);
    wT_all_kernel<<<229376 / 256, 256, 0, stream>>>(w1l, w1r, w2l, w2r, w3l, w3r,
                                                    w1lT, w1rT, w2lT, w2rT, w3lT, w3rT);

    const int nrb = (N + 127) / 128;
    const int gnb = (N + 63) / 64;     // node-blocks per slice

    // ---- layer 1: 128 -> 128
    gather_f8s<128><<<gnb * 4, 256, 0, stream>>>(xf8, meta, col, aggb, N);
    mfma_layer<128, 128, false, true><<<nrb * 1, 256, 0, stream>>>(
        xbf, aggb, w1lT, w1rT, b1, g1, be1, m1, v1, h1, h1f8, N);

    // ---- layer 2: 128 -> 256
    gather_f8s<128><<<gnb * 4, 256, 0, stream>>>(h1f8, meta, col, aggb, N);
    mfma_layer<128, 256, false, true><<<nrb * 2, 256, 0, stream>>>(
        h1, aggb, w2lT, w2rT, b2, g2, be2, m2, v2, h2, h2f8, N);

    // ---- layer 3: 256 -> 256
    gather_f8s<256><<<gnb * 8, 256, 0, stream>>>(h2f8, meta, col, aggb, N);
    mfma_layer<256, 256, true, false><<<nrb * 2, 256, 0, stream>>>(
        h2, aggb, w3lT, w3rT, b3, g3, be3, m3, v3, out, nullptr, N);
}

// Round 11
// 488.224 us; speedup vs baseline: 1.1069x; 1.1069x over previous
//
#include <hip/hip_runtime.h>

#define NNODES 100000
#define NEDGES 1600000
#define EPSV 1e-5f

#define NB   391      // buckets of 256 consecutive dst nodes: ceil(100000/256)
#define BCAP 4608     // bucket capacity; mean 4092, sigma ~64 -> 8-sigma margin
#define EPB  4096     // edges per partition workgroup

typedef __attribute__((ext_vector_type(8))) short bf16x8;
typedef __attribute__((ext_vector_type(4))) float f32x4;
typedef __attribute__((ext_vector_type(2))) float f32x2;

#if defined(__has_builtin)
#  if __has_builtin(__builtin_amdgcn_cvt_pk_f32_fp8) && __has_builtin(__builtin_amdgcn_cvt_pk_fp8_f32)
#    define HAS_FP8_CVT 1
#  endif
#endif
#ifndef HAS_FP8_CVT
#  define HAS_FP8_CVT 0
#endif

// ----------------------------------------------------------- bf16 helpers ---
__device__ __forceinline__ ushort f2bf(float f) {
    union { float f; uint u; } c; c.f = f;
    uint u = c.u;
    return (ushort)((u + 0x7fffu + ((u >> 16) & 1u)) >> 16);
}
__device__ __forceinline__ uint pack2(float f0, float f1) {
    return (uint)f2bf(f0) | ((uint)f2bf(f1) << 16);
}

// ------------------------------------------------------------ fp8 helpers ---
// OCP e4m3fn. HW path: v_cvt_pk_{f32_fp8,fp8_f32}. Manual fallback: FTZ+sat.
#if !HAS_FP8_CVT
__device__ __forceinline__ float fp8_dec1(uint b) {
    uint e = (b >> 3) & 0xFu, m = b & 7u, s = b >> 7;
    union { uint u; float f; } c;
    c.u = e ? ((s << 31) | ((e + 120u) << 23) | (m << 20)) : (s << 31);
    return c.f;
}
__device__ __forceinline__ uint fp8_enc1(float x) {
    union { float f; uint u; } c; c.f = x;
    uint u = c.u, s = u >> 31;
    float ax = fabsf(x);
    if (ax < 0.015625f) return s << 7;        // FTZ below 2^-6
    if (ax > 448.0f)    return (s << 7) | 0x7Eu;
    u = u + 0x7FFFFu + ((u >> 20) & 1u);      // RNE at bit 20
    uint e = ((u >> 23) & 0xFFu) - 120u;
    uint m = (u >> 20) & 7u;
    if (e > 15u) return (s << 7) | 0x7Eu;
    return (s << 7) | (e << 3) | m;
}
#endif

// decode 8 fp8 from uint2, packed-accumulate into 4 f32x2 (v_pk_add_f32)
__device__ __forceinline__ void accf8p(f32x2* a, uint2 v) {
#if HAS_FP8_CVT
    a[0] += __builtin_amdgcn_cvt_pk_f32_fp8((int)v.x, false);
    a[1] += __builtin_amdgcn_cvt_pk_f32_fp8((int)v.x, true);
    a[2] += __builtin_amdgcn_cvt_pk_f32_fp8((int)v.y, false);
    a[3] += __builtin_amdgcn_cvt_pk_f32_fp8((int)v.y, true);
#else
    a[0] += (f32x2){fp8_dec1(v.x & 0xFFu), fp8_dec1((v.x >> 8) & 0xFFu)};
    a[1] += (f32x2){fp8_dec1((v.x >> 16) & 0xFFu), fp8_dec1(v.x >> 24)};
    a[2] += (f32x2){fp8_dec1(v.y & 0xFFu), fp8_dec1((v.y >> 8) & 0xFFu)};
    a[3] += (f32x2){fp8_dec1((v.y >> 16) & 0xFFu), fp8_dec1(v.y >> 24)};
#endif
}

__device__ __forceinline__ uint f2fp8(float f) {
#if HAS_FP8_CVT
    return ((uint)__builtin_amdgcn_cvt_pk_fp8_f32(f, f, 0, false)) & 0xFFu;
#else
    return fp8_enc1(f);
#endif
}

__device__ __forceinline__ uint packf8_4(float f0, float f1, float f2, float f3) {
#if HAS_FP8_CVT
    int r = 0;
    r = __builtin_amdgcn_cvt_pk_fp8_f32(f0, f1, r, false);
    r = __builtin_amdgcn_cvt_pk_fp8_f32(f2, f3, r, true);
    return (uint)r;
#else
    return fp8_enc1(f0) | (fp8_enc1(f1) << 8) | (fp8_enc1(f2) << 16) | (fp8_enc1(f3) << 24);
#endif
}

// --------------------------------------------------- async global->LDS ------
__device__ __forceinline__ void load_lds16(const ushort* g, ushort* l) {
    __builtin_amdgcn_global_load_lds(
        (const __attribute__((address_space(1))) void*)g,
        (__attribute__((address_space(3))) void*)l,
        16, 0, 0);
}

// ------------------------------------------------- CSR build, bucketed ------
__global__ __launch_bounds__(256) void part_kernel(
    const int* __restrict__ src, const int* __restrict__ dst,
    int* __restrict__ cursor, uint2* __restrict__ pairs, int E)
{
    __shared__ int lcnt[NB];
    __shared__ int lbase[NB];
    const int t = threadIdx.x;
    for (int i = t; i < NB; i += 256) lcnt[i] = 0;
    __syncthreads();

    const int base = blockIdx.x * EPB;
    const int lim  = min(base + EPB, E);

    for (int e = base + t; e < lim; e += 256)
        atomicAdd(&lcnt[((unsigned)dst[e]) >> 8], 1);
    __syncthreads();

    for (int i = t; i < NB; i += 256) {
        int c = lcnt[i];
        lbase[i] = c ? atomicAdd(&cursor[i], c) : 0;
        lcnt[i] = 0;
    }
    __syncthreads();

    for (int e = base + t; e < lim; e += 256) {
        int d = dst[e];
        int b = ((unsigned)d) >> 8;
        int p = lbase[b] + atomicAdd(&lcnt[b], 1);
        if (p < BCAP) pairs[(size_t)b * BCAP + p] = make_uint2((uint)src[e], (uint)d);
    }
}

__global__ __launch_bounds__(512) void bscan_kernel(const int* __restrict__ cursor,
                                                    int* __restrict__ colBase)
{
    __shared__ int s[512];
    int t = threadIdx.x;
    int v = (t < NB) ? min(cursor[t], BCAP) : 0;
    s[t] = v;
    __syncthreads();
    #pragma unroll
    for (int off = 1; off < 512; off <<= 1) {
        int a = (t >= off) ? s[t - off] : 0;
        __syncthreads();
        s[t] += a;
        __syncthreads();
    }
    if (t < NB) colBase[t] = s[t] - v;
}

__global__ __launch_bounds__(256) void csr_fin_kernel(
    const uint2* __restrict__ pairs, const int* __restrict__ cursor,
    const int* __restrict__ colBase, uint2* __restrict__ meta,
    int* __restrict__ col, int n)
{
    __shared__ int lcnt[256];
    __shared__ int lofs[256];
    const int b = blockIdx.x;
    const int t = threadIdx.x;
    const int ecnt  = min(cursor[b], BCAP);
    const int cbase = colBase[b];
    const uint2* __restrict__ pp = pairs + (size_t)b * BCAP;

    lcnt[t] = 0;
    __syncthreads();
    for (int e = t; e < ecnt; e += 256)
        atomicAdd(&lcnt[pp[e].y & 255u], 1);
    __syncthreads();

    const int v = lcnt[t];
    lofs[t] = v;
    __syncthreads();
    #pragma unroll
    for (int off = 1; off < 256; off <<= 1) {
        int a = (t >= off) ? lofs[t - off] : 0;
        __syncthreads();
        lofs[t] += a;
        __syncthreads();
    }
    const int excl = lofs[t] - v;

    const int node = (b << 8) + t;
    if (node < n)
        meta[node] = make_uint2((uint)(cbase + excl), (uint)v);   // (beg, cnt)
    __syncthreads();
    lcnt[t] = excl;                      // reuse as cursor
    __syncthreads();

    for (int e = t; e < ecnt; e += 256) {
        uint2 pr = pp[e];
        int p = cbase + atomicAdd(&lcnt[pr.y & 255u], 1);
        col[p] = (int)pr.x;
    }
}

// ------------------------------------------------------------ conversions ---
// x fp32 -> xbf (bf16, GEMM self-term) + xf8 (fp8, row-major, gather side)
__global__ void cvt_x_kernel(const float* __restrict__ in, ushort* __restrict__ outb,
                             unsigned char* __restrict__ out8, int n4) {
    int i = blockIdx.x * blockDim.x + threadIdx.x;
    if (i < n4) {
        float4 v = ((const float4*)in)[i];
        ushort4 o;
        o.x = f2bf(v.x); o.y = f2bf(v.y); o.z = f2bf(v.z); o.w = f2bf(v.w);
        ((ushort4*)outb)[i] = o;
        ((uint*)out8)[i] = packf8_4(v.x, v.y, v.z, v.w);
    }
}

// All six weight transposes (w[K][Nout] fp32 -> wt[Nout][K] bf16) in one launch.
__global__ void wT_all_kernel(
    const float* __restrict__ w1l, const float* __restrict__ w1r,
    const float* __restrict__ w2l, const float* __restrict__ w2r,
    const float* __restrict__ w3l, const float* __restrict__ w3r,
    ushort* __restrict__ t1l, ushort* __restrict__ t1r,
    ushort* __restrict__ t2l, ushort* __restrict__ t2r,
    ushort* __restrict__ t3l, ushort* __restrict__ t3r)
{
    int idx = blockIdx.x * blockDim.x + threadIdx.x;
    const float* w; ushort* wt; int K, Nout, i;
    if      (idx <  16384) { w = w1l; wt = t1l; K = 128; Nout = 128; i = idx; }
    else if (idx <  32768) { w = w1r; wt = t1r; K = 128; Nout = 128; i = idx - 16384; }
    else if (idx <  65536) { w = w2l; wt = t2l; K = 128; Nout = 256; i = idx - 32768; }
    else if (idx <  98304) { w = w2r; wt = t2r; K = 128; Nout = 256; i = idx - 65536; }
    else if (idx < 163840) { w = w3l; wt = t3l; K = 256; Nout = 256; i = idx - 98304; }
    else if (idx < 229376) { w = w3r; wt = t3r; K = 256; Nout = 256; i = idx - 163840; }
    else return;
    int k = i / Nout, n = i - k * Nout;
    wt[(size_t)n * K + k] = f2bf(w[i]);
}

// ---------------------------------------------------------- gather (mean) ---
// fp8 input rows (D bytes), D/8 lanes per node, 8 B (uint2) per lane.
// Round-8 proven body. `base` allows splitting one logical gather into
// multiple dispatches over node sub-ranges (profiling visibility; the
// sub-ranges are independent).
template<int D>
__global__ __launch_bounds__(256) void gather_f8(
    const unsigned char* __restrict__ x, const uint2* __restrict__ meta,
    const int* __restrict__ col, ushort* __restrict__ agg, int base, int n)
{
    constexpr int TPN = D / 8;                 // 16 (D=128) or 32 (D=256)
    constexpr int NPB = 256 / TPN;
    const int node = base + blockIdx.x * NPB + threadIdx.x / TPN;
    const int lane = threadIdx.x % TPN;
    if (node >= n) return;

    const uint2 m  = meta[node];               // (beg, cnt) — single 8B load
    const int  c   = (int)m.y;
    int        e   = (int)m.x;
    const int  end = e + c;
    const uint boff = (uint)lane * 8u;

    f32x2 a[4];
    #pragma unroll
    for (int i = 0; i < 4; ++i) a[i] = (f32x2)0.0f;

    while (e + 15 < end) {
        uint2 r[16];
        #pragma unroll
        for (int i = 0; i < 16; ++i)
            r[i] = *(const uint2*)(x + (uint)col[e + i] * (uint)D + boff);
        #pragma unroll
        for (int i = 0; i < 16; ++i) accf8p(a, r[i]);
        e += 16;
    }
    if (e + 7 < end) {
        uint2 r[8];
        #pragma unroll
        for (int i = 0; i < 8; ++i)
            r[i] = *(const uint2*)(x + (uint)col[e + i] * (uint)D + boff);
        #pragma unroll
        for (int i = 0; i < 8; ++i) accf8p(a, r[i]);
        e += 8;
    }
    for (; e + 1 < end; e += 2) {
        uint2 v0 = *(const uint2*)(x + (uint)col[e]     * (uint)D + boff);
        uint2 v1 = *(const uint2*)(x + (uint)col[e + 1] * (uint)D + boff);
        accf8p(a, v0); accf8p(a, v1);
    }
    if (e < end) {
        uint2 v = *(const uint2*)(x + (uint)col[e] * (uint)D + boff);
        accf8p(a, v);
    }

    const float inv = 1.0f / fmaxf((float)c, 1.0f);
    uint4 o;
    o.x = pack2(a[0][0] * inv, a[0][1] * inv);
    o.y = pack2(a[1][0] * inv, a[1][1] * inv);
    o.z = pack2(a[2][0] * inv, a[2][1] * inv);
    o.w = pack2(a[3][0] * inv, a[3][1] * inv);
    ((uint4*)agg)[(size_t)node * TPN + lane] = o;
}

// ---------------------------------------------- fused SAGE layer (MFMA) -----
// out = bn(relu( agg @ wl + xin @ wr + bias )); optional fp8 copy for the
// next layer's gather.
//
// m97 structure: global_load_lds(16B) staging into LINEAR LDS, BK=64,
// XOR-swizzle (row&7) applied to the global SOURCE chunk at stage time and
// to the ds_read_b128 chunk at read time (rule #21: both-sides-or-neither).
template<int DIN, int DOUT, bool OUTF32, bool WRITE8>
__global__ __launch_bounds__(256) void mfma_layer(
    const ushort* __restrict__ xin, const ushort* __restrict__ agg,
    const ushort* __restrict__ wlT, const ushort* __restrict__ wrT,
    const float* __restrict__ bias, const float* __restrict__ gamma,
    const float* __restrict__ beta, const float* __restrict__ rmean,
    const float* __restrict__ rvar, void* __restrict__ outp,
    unsigned char* __restrict__ out8, int M)
{
    constexpr int BM = 128, BN = 128, BK = 64;
    constexpr int NBY = DOUT / BN;             // 1 or 2 (power of 2)
    __shared__ ushort As[BM * BK];             // 16 KB, linear + src-side swizzle
    __shared__ ushort Bs[BN * BK];             // 16 KB

    const int tid  = threadIdx.x;
    const int lane = tid & 63;
    const int wid  = tid >> 6;
    const int wm   = (wid & 1) * 64;
    const int wn   = (wid >> 1) * 64;
    const int lr   = lane & 15;
    const int quad = lane >> 4;

    const int row0 = (blockIdx.x / NBY) * BM;
    const int col0 = (blockIdx.x % NBY) * BN;

    f32x4 acc[4][4] = {};

    const int srow = tid >> 3;                       // + r*32 per round
    const int schk = (tid & 7) ^ (srow & 7);         // swizzled source chunk

    #pragma unroll
    for (int phase = 0; phase < 2; ++phase) {
        const ushort* __restrict__ A = phase ? xin : agg;
        const ushort* __restrict__ W = phase ? wrT : wlT;

        for (int k0 = 0; k0 < DIN; k0 += BK) {
            __syncthreads();   // previous iteration's LDS reads complete
            #pragma unroll
            for (int r = 0; r < 4; ++r) {
                const int row = srow + r * 32;
                int gra = row0 + row; gra = gra < M ? gra : M - 1;
                load_lds16(A + (size_t)gra * DIN + k0 + schk * 8,
                           &As[(r * 256 + tid) * 8]);
                load_lds16(W + (size_t)(col0 + row) * DIN + k0 + schk * 8,
                           &Bs[(r * 256 + tid) * 8]);
            }
            __syncthreads();   // compiler drains vmcnt(0) here -> tiles ready

            #pragma unroll
            for (int sub = 0; sub < 2; ++sub) {
                bf16x8 af[4], bf[4];
                #pragma unroll
                for (int t = 0; t < 4; ++t) {
                    const int ra = wm + t * 16 + lr;
                    const int rb = wn + t * 16 + lr;
                    const int ca = ((sub << 2) | quad) ^ (ra & 7);
                    const int cb = ((sub << 2) | quad) ^ (rb & 7);
                    af[t] = *(const bf16x8*)&As[ra * BK + ca * 8];
                    bf[t] = *(const bf16x8*)&Bs[rb * BK + cb * 8];
                }
                #pragma unroll
                for (int mt = 0; mt < 4; ++mt)
                    #pragma unroll
                    for (int nt = 0; nt < 4; ++nt)
                        acc[mt][nt] = __builtin_amdgcn_mfma_f32_16x16x32_bf16(
                            af[mt], bf[nt], acc[mt][nt], 0, 0, 0);
            }
        }
    }

    float bj[4], sj[4], mj[4], bej[4];
    #pragma unroll
    for (int nt = 0; nt < 4; ++nt) {
        int gc = col0 + wn + nt * 16 + lr;
        bj[nt]  = bias[gc];
        sj[nt]  = rsqrtf(rvar[gc] + EPSV) * gamma[gc];
        mj[nt]  = rmean[gc];
        bej[nt] = beta[gc];
    }
    #pragma unroll
    for (int mt = 0; mt < 4; ++mt) {
        #pragma unroll
        for (int r = 0; r < 4; ++r) {
            int grow = row0 + wm + mt * 16 + quad * 4 + r;
            if (grow < M) {
                #pragma unroll
                for (int nt = 0; nt < 4; ++nt) {
                    int gc = col0 + wn + nt * 16 + lr;
                    float h = acc[mt][nt][r] + bj[nt];
                    h = fmaxf(h, 0.0f);
                    h = (h - mj[nt]) * sj[nt] + bej[nt];
                    if (OUTF32) ((float*)outp)[(size_t)grow * DOUT + gc] = h;
                    else        ((ushort*)outp)[(size_t)grow * DOUT + gc] = f2bf(h);
                    if (WRITE8) out8[(size_t)grow * DOUT + gc] = (unsigned char)f2fp8(h);
                }
            }
        }
    }
}

// ------------------------------------------------------------------ launch --
extern "C" void kernel_launch(void* const* d_in, const int* in_sizes, int n_in,
                              void* d_out, int out_size, void* d_ws, size_t ws_size,
                              hipStream_t stream) {
    const int N = NNODES;
    const int E = NEDGES;

    const float* x   = (const float*)d_in[0];
    const int*   ei  = (const int*)d_in[1];
    const int*   src = ei;
    const int*   dst = ei + E;

    const float* w1l = (const float*)d_in[2];
    const float* w1r = (const float*)d_in[3];
    const float* b1  = (const float*)d_in[4];
    const float* g1  = (const float*)d_in[5];
    const float* be1 = (const float*)d_in[6];
    const float* m1  = (const float*)d_in[7];
    const float* v1  = (const float*)d_in[8];

    const float* w2l = (const float*)d_in[9];
    const float* w2r = (const float*)d_in[10];
    const float* b2  = (const float*)d_in[11];
    const float* g2  = (const float*)d_in[12];
    const float* be2 = (const float*)d_in[13];
    const float* m2  = (const float*)d_in[14];
    const float* v2  = (const float*)d_in[15];

    const float* w3l = (const float*)d_in[16];
    const float* w3r = (const float*)d_in[17];
    const float* b3  = (const float*)d_in[18];
    const float* g3  = (const float*)d_in[19];
    const float* be3 = (const float*)d_in[20];
    const float* m3  = (const float*)d_in[21];
    const float* v3  = (const float*)d_in[22];

    float* out = (float*)d_out;

    // ---- workspace layout (16B-aligned segments) ----
    // pairs region (14.41 MB) is dead after csr_fin -> reused for xf8 then h1f8.
    char*   wp      = (char*)d_ws;
    uint2*  meta    = (uint2*)wp;   wp += (size_t)N * sizeof(uint2);   // (beg,cnt)
    int*    cursor  = (int*)wp;     wp += 512 * sizeof(int);
    int*    colBase = (int*)wp;     wp += 512 * sizeof(int);
    int*    col     = (int*)wp;     wp += (size_t)E * sizeof(int);
    uint2*  pairs   = (uint2*)wp;   wp += (size_t)NB * BCAP * sizeof(uint2);
    ushort* xbf     = (ushort*)wp;  wp += (size_t)N * 128 * sizeof(ushort);
    ushort* h1      = (ushort*)wp;  wp += (size_t)N * 128 * sizeof(ushort);
    ushort* h2      = (ushort*)wp;  wp += (size_t)N * 256 * sizeof(ushort);
    ushort* aggb    = (ushort*)wp;  wp += (size_t)N * 256 * sizeof(ushort);
    unsigned char* h2f8 = (unsigned char*)wp; wp += (size_t)N * 256;
    ushort* w1lT    = (ushort*)wp;  wp += 128 * 128 * sizeof(ushort);
    ushort* w1rT    = (ushort*)wp;  wp += 128 * 128 * sizeof(ushort);
    ushort* w2lT    = (ushort*)wp;  wp += 256 * 128 * sizeof(ushort);
    ushort* w2rT    = (ushort*)wp;  wp += 256 * 128 * sizeof(ushort);
    ushort* w3lT    = (ushort*)wp;  wp += 256 * 256 * sizeof(ushort);
    ushort* w3rT    = (ushort*)wp;

    unsigned char* xf8  = (unsigned char*)pairs;   // 12.8 MB <= 14.41 MB
    unsigned char* h1f8 = (unsigned char*)pairs;   // after xf8 is dead

    const int T = 256;

    // ---- CSR build (bucketed) ----
    hipMemsetAsync(cursor, 0, 512 * sizeof(int), stream);
    part_kernel<<<(E + EPB - 1) / EPB, 256, 0, stream>>>(src, dst, cursor, pairs, E);
    bscan_kernel<<<1, 512, 0, stream>>>(cursor, colBase);
    csr_fin_kernel<<<NB, 256, 0, stream>>>(pairs, cursor, colBase, meta, col, N);

    // ---- conversions (xf8 write must follow csr_fin: aliases pairs) ----
    cvt_x_kernel<<<((N * 128 / 4) + T - 1) / T, T, 0, stream>>>(x, xbf, xf8, N * 128 / 4);
    wT_all_kernel<<<229376 / 256, 256, 0, stream>>>(w1l, w1r, w2l, w2r, w3l, w3r,
                                                    w1lT, w1rT, w2lT, w2rT, w3lT, w3rT);

    const int nrb = (N + 127) / 128;
    const int NH  = 50000;             // node-range split point for g256

    // ---- layer 1: 128 -> 128
    gather_f8<128><<<(N + 15) / 16, 256, 0, stream>>>(xf8, meta, col, aggb, 0, N);
    mfma_layer<128, 128, false, true><<<nrb * 1, 256, 0, stream>>>(
        xbf, aggb, w1lT, w1rT, b1, g1, be1, m1, v1, h1, h1f8, N);

    // ---- layer 2: 128 -> 256
    gather_f8<128><<<(N + 15) / 16, 256, 0, stream>>>(h1f8, meta, col, aggb, 0, N);
    mfma_layer<128, 256, false, true><<<nrb * 2, 256, 0, stream>>>(
        h1, aggb, w2lT, w2rT, b2, g2, be2, m2, v2, h2, h2f8, N);

    // ---- layer 3: 256 -> 256 (gather split into two independent halves,
    //      same total work — unmasks the mid-tier dispatches in top-5 profile)
    gather_f8<256><<<(NH + 7) / 8, 256, 0, stream>>>(h2f8, meta, col, aggb, 0, NH);
    gather_f8<256><<<(N - NH + 7) / 8, 256, 0, stream>>>(h2f8, meta, col, aggb, NH, N);
    mfma_layer<256, 256, true, false><<<nrb * 2, 256, 0, stream>>>(
        h2, aggb, w3lT, w3rT, b3, g3, be3, m3, v3, out, nullptr, N);
}

// Round 12
// 475.386 us; speedup vs baseline: 1.1368x; 1.0270x over previous
//
#include <hip/hip_runtime.h>

#define NNODES 100000
#define NEDGES 1600000
#define EPSV 1e-5f

#define NB   391      // buckets of 256 consecutive dst nodes: ceil(100000/256)
#define BCAP 4608     // bucket capacity; mean 4092, sigma ~64 -> 8-sigma margin
#define EPB  4096     // edges per partition workgroup

#define PART_BLKS 391     // ceil(NEDGES / EPB)
#define CVT_BLKS  12500   // NNODES*128/4 / 256
#define WT_BLKS   896     // 229376 / 256

typedef __attribute__((ext_vector_type(8))) short bf16x8;
typedef __attribute__((ext_vector_type(4))) float f32x4;
typedef __attribute__((ext_vector_type(2))) float f32x2;

#if defined(__has_builtin)
#  if __has_builtin(__builtin_amdgcn_cvt_pk_f32_fp8) && __has_builtin(__builtin_amdgcn_cvt_pk_fp8_f32)
#    define HAS_FP8_CVT 1
#  endif
#endif
#ifndef HAS_FP8_CVT
#  define HAS_FP8_CVT 0
#endif

// ----------------------------------------------------------- bf16 helpers ---
__device__ __forceinline__ ushort f2bf(float f) {
    union { float f; uint u; } c; c.f = f;
    uint u = c.u;
    return (ushort)((u + 0x7fffu + ((u >> 16) & 1u)) >> 16);
}
__device__ __forceinline__ uint pack2(float f0, float f1) {
    return (uint)f2bf(f0) | ((uint)f2bf(f1) << 16);
}

// ------------------------------------------------------------ fp8 helpers ---
// OCP e4m3fn. HW path: v_cvt_pk_{f32_fp8,fp8_f32}. Manual fallback: FTZ+sat.
#if !HAS_FP8_CVT
__device__ __forceinline__ float fp8_dec1(uint b) {
    uint e = (b >> 3) & 0xFu, m = b & 7u, s = b >> 7;
    union { uint u; float f; } c;
    c.u = e ? ((s << 31) | ((e + 120u) << 23) | (m << 20)) : (s << 31);
    return c.f;
}
__device__ __forceinline__ uint fp8_enc1(float x) {
    union { float f; uint u; } c; c.f = x;
    uint u = c.u, s = u >> 31;
    float ax = fabsf(x);
    if (ax < 0.015625f) return s << 7;        // FTZ below 2^-6
    if (ax > 448.0f)    return (s << 7) | 0x7Eu;
    u = u + 0x7FFFFu + ((u >> 20) & 1u);      // RNE at bit 20
    uint e = ((u >> 23) & 0xFFu) - 120u;
    uint m = (u >> 20) & 7u;
    if (e > 15u) return (s << 7) | 0x7Eu;
    return (s << 7) | (e << 3) | m;
}
#endif

// decode 8 fp8 from uint2, packed-accumulate into 4 f32x2 (v_pk_add_f32)
__device__ __forceinline__ void accf8p(f32x2* a, uint2 v) {
#if HAS_FP8_CVT
    a[0] += __builtin_amdgcn_cvt_pk_f32_fp8((int)v.x, false);
    a[1] += __builtin_amdgcn_cvt_pk_f32_fp8((int)v.x, true);
    a[2] += __builtin_amdgcn_cvt_pk_f32_fp8((int)v.y, false);
    a[3] += __builtin_amdgcn_cvt_pk_f32_fp8((int)v.y, true);
#else
    a[0] += (f32x2){fp8_dec1(v.x & 0xFFu), fp8_dec1((v.x >> 8) & 0xFFu)};
    a[1] += (f32x2){fp8_dec1((v.x >> 16) & 0xFFu), fp8_dec1(v.x >> 24)};
    a[2] += (f32x2){fp8_dec1(v.y & 0xFFu), fp8_dec1((v.y >> 8) & 0xFFu)};
    a[3] += (f32x2){fp8_dec1((v.y >> 16) & 0xFFu), fp8_dec1(v.y >> 24)};
#endif
}

__device__ __forceinline__ uint f2fp8(float f) {
#if HAS_FP8_CVT
    return ((uint)__builtin_amdgcn_cvt_pk_fp8_f32(f, f, 0, false)) & 0xFFu;
#else
    return fp8_enc1(f);
#endif
}

__device__ __forceinline__ uint packf8_4(float f0, float f1, float f2, float f3) {
#if HAS_FP8_CVT
    int r = 0;
    r = __builtin_amdgcn_cvt_pk_fp8_f32(f0, f1, r, false);
    r = __builtin_amdgcn_cvt_pk_fp8_f32(f2, f3, r, true);
    return (uint)r;
#else
    return fp8_enc1(f0) | (fp8_enc1(f1) << 8) | (fp8_enc1(f2) << 16) | (fp8_enc1(f3) << 24);
#endif
}

// --------------------------------------------------- async global->LDS ------
__device__ __forceinline__ void load_lds16(const ushort* g, ushort* l) {
    __builtin_amdgcn_global_load_lds(
        (const __attribute__((address_space(1))) void*)g,
        (__attribute__((address_space(3))) void*)l,
        16, 0, 0);
}

// --------------------------------------- fused pre-pass: part | cvt | wT ----
// part_kernel (CSR bucketing, atomic-bound) is data-independent of the
// x/weight conversions (BW-bound) now that xf8 no longer aliases pairs
// (it aliases h2, which is first written by layer-2's mfma, long after g1
// consumed xf8). Fusing them into one block-range-specialized launch
// overlaps the two: conversions hide under the bucketing atomics.
__global__ __launch_bounds__(256) void pre_kernel(
    const int* __restrict__ src, const int* __restrict__ dst,
    int* __restrict__ cursor, uint2* __restrict__ pairs, int E,
    const float* __restrict__ x, ushort* __restrict__ xbf,
    unsigned char* __restrict__ xf8, int n4,
    const float* __restrict__ w1l, const float* __restrict__ w1r,
    const float* __restrict__ w2l, const float* __restrict__ w2r,
    const float* __restrict__ w3l, const float* __restrict__ w3r,
    ushort* __restrict__ t1l, ushort* __restrict__ t1r,
    ushort* __restrict__ t2l, ushort* __restrict__ t2r,
    ushort* __restrict__ t3l, ushort* __restrict__ t3r)
{
    const int t = threadIdx.x;

    if (blockIdx.x < PART_BLKS) {
        // ---------------- CSR partition (bucketed) ----------------
        __shared__ int lcnt[NB];
        __shared__ int lbase[NB];
        for (int i = t; i < NB; i += 256) lcnt[i] = 0;
        __syncthreads();

        const int base = blockIdx.x * EPB;
        const int lim  = min(base + EPB, E);

        for (int e = base + t; e < lim; e += 256)
            atomicAdd(&lcnt[((unsigned)dst[e]) >> 8], 1);
        __syncthreads();

        for (int i = t; i < NB; i += 256) {
            int c = lcnt[i];
            lbase[i] = c ? atomicAdd(&cursor[i], c) : 0;
            lcnt[i] = 0;
        }
        __syncthreads();

        for (int e = base + t; e < lim; e += 256) {
            int d = dst[e];
            int b = ((unsigned)d) >> 8;
            int p = lbase[b] + atomicAdd(&lcnt[b], 1);
            if (p < BCAP) pairs[(size_t)b * BCAP + p] = make_uint2((uint)src[e], (uint)d);
        }
    } else if (blockIdx.x < PART_BLKS + CVT_BLKS) {
        // ---------------- x fp32 -> bf16 + fp8 ----------------
        int i = (blockIdx.x - PART_BLKS) * 256 + t;
        if (i < n4) {
            float4 v = ((const float4*)x)[i];
            ushort4 o;
            o.x = f2bf(v.x); o.y = f2bf(v.y); o.z = f2bf(v.z); o.w = f2bf(v.w);
            ((ushort4*)xbf)[i] = o;
            ((uint*)xf8)[i] = packf8_4(v.x, v.y, v.z, v.w);
        }
    } else {
        // ---------------- weight transposes ----------------
        int idx = (blockIdx.x - PART_BLKS - CVT_BLKS) * 256 + t;
        const float* w; ushort* wt; int K, Nout, i;
        if      (idx <  16384) { w = w1l; wt = t1l; K = 128; Nout = 128; i = idx; }
        else if (idx <  32768) { w = w1r; wt = t1r; K = 128; Nout = 128; i = idx - 16384; }
        else if (idx <  65536) { w = w2l; wt = t2l; K = 128; Nout = 256; i = idx - 32768; }
        else if (idx <  98304) { w = w2r; wt = t2r; K = 128; Nout = 256; i = idx - 65536; }
        else if (idx < 163840) { w = w3l; wt = t3l; K = 256; Nout = 256; i = idx - 98304; }
        else if (idx < 229376) { w = w3r; wt = t3r; K = 256; Nout = 256; i = idx - 163840; }
        else return;
        int k = i / Nout, n = i - k * Nout;
        wt[(size_t)n * K + k] = f2bf(w[i]);
    }
}

__global__ __launch_bounds__(512) void bscan_kernel(const int* __restrict__ cursor,
                                                    int* __restrict__ colBase)
{
    __shared__ int s[512];
    int t = threadIdx.x;
    int v = (t < NB) ? min(cursor[t], BCAP) : 0;
    s[t] = v;
    __syncthreads();
    #pragma unroll
    for (int off = 1; off < 512; off <<= 1) {
        int a = (t >= off) ? s[t - off] : 0;
        __syncthreads();
        s[t] += a;
        __syncthreads();
    }
    if (t < NB) colBase[t] = s[t] - v;
}

__global__ __launch_bounds__(256) void csr_fin_kernel(
    const uint2* __restrict__ pairs, const int* __restrict__ cursor,
    const int* __restrict__ colBase, uint2* __restrict__ meta,
    int* __restrict__ col, int n)
{
    __shared__ int lcnt[256];
    __shared__ int lofs[256];
    const int b = blockIdx.x;
    const int t = threadIdx.x;
    const int ecnt  = min(cursor[b], BCAP);
    const int cbase = colBase[b];
    const uint2* __restrict__ pp = pairs + (size_t)b * BCAP;

    lcnt[t] = 0;
    __syncthreads();
    for (int e = t; e < ecnt; e += 256)
        atomicAdd(&lcnt[pp[e].y & 255u], 1);
    __syncthreads();

    const int v = lcnt[t];
    lofs[t] = v;
    __syncthreads();
    #pragma unroll
    for (int off = 1; off < 256; off <<= 1) {
        int a = (t >= off) ? lofs[t - off] : 0;
        __syncthreads();
        lofs[t] += a;
        __syncthreads();
    }
    const int excl = lofs[t] - v;

    const int node = (b << 8) + t;
    if (node < n)
        meta[node] = make_uint2((uint)(cbase + excl), (uint)v);   // (beg, cnt)
    __syncthreads();
    lcnt[t] = excl;                      // reuse as cursor
    __syncthreads();

    for (int e = t; e < ecnt; e += 256) {
        uint2 pr = pp[e];
        int p = cbase + atomicAdd(&lcnt[pr.y & 255u], 1);
        col[p] = (int)pr.x;
    }
}

// ---------------------------------------------------------- gather (mean) ---
// fp8 input rows (D bytes), D/8 lanes per node, 8 B (uint2) per lane.
// Round-8 proven body (at its random-access pattern roofline per r4-r9).
template<int D>
__global__ __launch_bounds__(256) void gather_f8(
    const unsigned char* __restrict__ x, const uint2* __restrict__ meta,
    const int* __restrict__ col, ushort* __restrict__ agg, int n)
{
    constexpr int TPN = D / 8;                 // 16 (D=128) or 32 (D=256)
    constexpr int NPB = 256 / TPN;
    const int node = blockIdx.x * NPB + threadIdx.x / TPN;
    const int lane = threadIdx.x % TPN;
    if (node >= n) return;

    const uint2 m  = meta[node];               // (beg, cnt) — single 8B load
    const int  c   = (int)m.y;
    int        e   = (int)m.x;
    const int  end = e + c;
    const uint boff = (uint)lane * 8u;

    f32x2 a[4];
    #pragma unroll
    for (int i = 0; i < 4; ++i) a[i] = (f32x2)0.0f;

    while (e + 15 < end) {
        uint2 r[16];
        #pragma unroll
        for (int i = 0; i < 16; ++i)
            r[i] = *(const uint2*)(x + (uint)col[e + i] * (uint)D + boff);
        #pragma unroll
        for (int i = 0; i < 16; ++i) accf8p(a, r[i]);
        e += 16;
    }
    if (e + 7 < end) {
        uint2 r[8];
        #pragma unroll
        for (int i = 0; i < 8; ++i)
            r[i] = *(const uint2*)(x + (uint)col[e + i] * (uint)D + boff);
        #pragma unroll
        for (int i = 0; i < 8; ++i) accf8p(a, r[i]);
        e += 8;
    }
    for (; e + 1 < end; e += 2) {
        uint2 v0 = *(const uint2*)(x + (uint)col[e]     * (uint)D + boff);
        uint2 v1 = *(const uint2*)(x + (uint)col[e + 1] * (uint)D + boff);
        accf8p(a, v0); accf8p(a, v1);
    }
    if (e < end) {
        uint2 v = *(const uint2*)(x + (uint)col[e] * (uint)D + boff);
        accf8p(a, v);
    }

    const float inv = 1.0f / fmaxf((float)c, 1.0f);
    uint4 o;
    o.x = pack2(a[0][0] * inv, a[0][1] * inv);
    o.y = pack2(a[1][0] * inv, a[1][1] * inv);
    o.z = pack2(a[2][0] * inv, a[2][1] * inv);
    o.w = pack2(a[3][0] * inv, a[3][1] * inv);
    ((uint4*)agg)[(size_t)node * TPN + lane] = o;
}

// ---------------------------------------------- fused SAGE layer (MFMA) -----
// out = bn(relu( agg @ wl + xin @ wr + bias )); optional fp8 copy for the
// next layer's gather.
//
// m97 structure: global_load_lds(16B) staging into LINEAR LDS, BK=64,
// XOR-swizzle (row&7) applied to the global SOURCE chunk at stage time and
// to the ds_read_b128 chunk at read time (rule #21: both-sides-or-neither).
template<int DIN, int DOUT, bool OUTF32, bool WRITE8>
__global__ __launch_bounds__(256) void mfma_layer(
    const ushort* __restrict__ xin, const ushort* __restrict__ agg,
    const ushort* __restrict__ wlT, const ushort* __restrict__ wrT,
    const float* __restrict__ bias, const float* __restrict__ gamma,
    const float* __restrict__ beta, const float* __restrict__ rmean,
    const float* __restrict__ rvar, void* __restrict__ outp,
    unsigned char* __restrict__ out8, int M)
{
    constexpr int BM = 128, BN = 128, BK = 64;
    constexpr int NBY = DOUT / BN;             // 1 or 2 (power of 2)
    __shared__ ushort As[BM * BK];             // 16 KB, linear + src-side swizzle
    __shared__ ushort Bs[BN * BK];             // 16 KB

    const int tid  = threadIdx.x;
    const int lane = tid & 63;
    const int wid  = tid >> 6;
    const int wm   = (wid & 1) * 64;
    const int wn   = (wid >> 1) * 64;
    const int lr   = lane & 15;
    const int quad = lane >> 4;

    const int row0 = (blockIdx.x / NBY) * BM;
    const int col0 = (blockIdx.x % NBY) * BN;

    f32x4 acc[4][4] = {};

    const int srow = tid >> 3;                       // + r*32 per round
    const int schk = (tid & 7) ^ (srow & 7);         // swizzled source chunk

    #pragma unroll
    for (int phase = 0; phase < 2; ++phase) {
        const ushort* __restrict__ A = phase ? xin : agg;
        const ushort* __restrict__ W = phase ? wrT : wlT;

        for (int k0 = 0; k0 < DIN; k0 += BK) {
            __syncthreads();   // previous iteration's LDS reads complete
            #pragma unroll
            for (int r = 0; r < 4; ++r) {
                const int row = srow + r * 32;
                int gra = row0 + row; gra = gra < M ? gra : M - 1;
                load_lds16(A + (size_t)gra * DIN + k0 + schk * 8,
                           &As[(r * 256 + tid) * 8]);
                load_lds16(W + (size_t)(col0 + row) * DIN + k0 + schk * 8,
                           &Bs[(r * 256 + tid) * 8]);
            }
            __syncthreads();   // compiler drains vmcnt(0) here -> tiles ready

            #pragma unroll
            for (int sub = 0; sub < 2; ++sub) {
                bf16x8 af[4], bf[4];
                #pragma unroll
                for (int t = 0; t < 4; ++t) {
                    const int ra = wm + t * 16 + lr;
                    const int rb = wn + t * 16 + lr;
                    const int ca = ((sub << 2) | quad) ^ (ra & 7);
                    const int cb = ((sub << 2) | quad) ^ (rb & 7);
                    af[t] = *(const bf16x8*)&As[ra * BK + ca * 8];
                    bf[t] = *(const bf16x8*)&Bs[rb * BK + cb * 8];
                }
                #pragma unroll
                for (int mt = 0; mt < 4; ++mt)
                    #pragma unroll
                    for (int nt = 0; nt < 4; ++nt)
                        acc[mt][nt] = __builtin_amdgcn_mfma_f32_16x16x32_bf16(
                            af[mt], bf[nt], acc[mt][nt], 0, 0, 0);
            }
        }
    }

    float bj[4], sj[4], mj[4], bej[4];
    #pragma unroll
    for (int nt = 0; nt < 4; ++nt) {
        int gc = col0 + wn + nt * 16 + lr;
        bj[nt]  = bias[gc];
        sj[nt]  = rsqrtf(rvar[gc] + EPSV) * gamma[gc];
        mj[nt]  = rmean[gc];
        bej[nt] = beta[gc];
    }
    #pragma unroll
    for (int mt = 0; mt < 4; ++mt) {
        #pragma unroll
        for (int r = 0; r < 4; ++r) {
            int grow = row0 + wm + mt * 16 + quad * 4 + r;
            if (grow < M) {
                #pragma unroll
                for (int nt = 0; nt < 4; ++nt) {
                    int gc = col0 + wn + nt * 16 + lr;
                    float h = acc[mt][nt][r] + bj[nt];
                    h = fmaxf(h, 0.0f);
                    h = (h - mj[nt]) * sj[nt] + bej[nt];
                    if (OUTF32) ((float*)outp)[(size_t)grow * DOUT + gc] = h;
                    else        ((ushort*)outp)[(size_t)grow * DOUT + gc] = f2bf(h);
                    if (WRITE8) out8[(size_t)grow * DOUT + gc] = (unsigned char)f2fp8(h);
                }
            }
        }
    }
}

// ------------------------------------------------------------------ launch --
extern "C" void kernel_launch(void* const* d_in, const int* in_sizes, int n_in,
                              void* d_out, int out_size, void* d_ws, size_t ws_size,
                              hipStream_t stream) {
    const int N = NNODES;
    const int E = NEDGES;

    const float* x   = (const float*)d_in[0];
    const int*   ei  = (const int*)d_in[1];
    const int*   src = ei;
    const int*   dst = ei + E;

    const float* w1l = (const float*)d_in[2];
    const float* w1r = (const float*)d_in[3];
    const float* b1  = (const float*)d_in[4];
    const float* g1  = (const float*)d_in[5];
    const float* be1 = (const float*)d_in[6];
    const float* m1  = (const float*)d_in[7];
    const float* v1  = (const float*)d_in[8];

    const float* w2l = (const float*)d_in[9];
    const float* w2r = (const float*)d_in[10];
    const float* b2  = (const float*)d_in[11];
    const float* g2  = (const float*)d_in[12];
    const float* be2 = (const float*)d_in[13];
    const float* m2  = (const float*)d_in[14];
    const float* v2  = (const float*)d_in[15];

    const float* w3l = (const float*)d_in[16];
    const float* w3r = (const float*)d_in[17];
    const float* b3  = (const float*)d_in[18];
    const float* g3  = (const float*)d_in[19];
    const float* be3 = (const float*)d_in[20];
    const float* m3  = (const float*)d_in[21];
    const float* v3  = (const float*)d_in[22];

    float* out = (float*)d_out;

    // ---- workspace layout (16B-aligned segments) ----
    // Aliases: h1f8 -> pairs (dead after csr_fin, written by M1 later);
    //          xf8  -> h2    (h2 first written by M2, after g1 consumed xf8).
    char*   wp      = (char*)d_ws;
    uint2*  meta    = (uint2*)wp;   wp += (size_t)N * sizeof(uint2);   // (beg,cnt)
    int*    cursor  = (int*)wp;     wp += 512 * sizeof(int);
    int*    colBase = (int*)wp;     wp += 512 * sizeof(int);
    int*    col     = (int*)wp;     wp += (size_t)E * sizeof(int);
    uint2*  pairs   = (uint2*)wp;   wp += (size_t)NB * BCAP * sizeof(uint2);
    ushort* xbf     = (ushort*)wp;  wp += (size_t)N * 128 * sizeof(ushort);
    ushort* h1      = (ushort*)wp;  wp += (size_t)N * 128 * sizeof(ushort);
    ushort* h2      = (ushort*)wp;  wp += (size_t)N * 256 * sizeof(ushort);
    ushort* aggb    = (ushort*)wp;  wp += (size_t)N * 256 * sizeof(ushort);
    unsigned char* h2f8 = (unsigned char*)wp; wp += (size_t)N * 256;
    ushort* w1lT    = (ushort*)wp;  wp += 128 * 128 * sizeof(ushort);
    ushort* w1rT    = (ushort*)wp;  wp += 128 * 128 * sizeof(ushort);
    ushort* w2lT    = (ushort*)wp;  wp += 256 * 128 * sizeof(ushort);
    ushort* w2rT    = (ushort*)wp;  wp += 256 * 128 * sizeof(ushort);
    ushort* w3lT    = (ushort*)wp;  wp += 256 * 256 * sizeof(ushort);
    ushort* w3rT    = (ushort*)wp;

    unsigned char* xf8  = (unsigned char*)h2;      // 12.8 MB <= 51.2 MB (dead before M2)
    unsigned char* h1f8 = (unsigned char*)pairs;   // 12.8 MB <= 14.41 MB (pairs dead)

    // ---- fused pre-pass: CSR bucketing | x conversion | weight transpose ----
    hipMemsetAsync(cursor, 0, 512 * sizeof(int), stream);
    pre_kernel<<<PART_BLKS + CVT_BLKS + WT_BLKS, 256, 0, stream>>>(
        src, dst, cursor, pairs, E,
        x, xbf, xf8, N * 128 / 4,
        w1l, w1r, w2l, w2r, w3l, w3r,
        w1lT, w1rT, w2lT, w2rT, w3lT, w3rT);
    bscan_kernel<<<1, 512, 0, stream>>>(cursor, colBase);
    csr_fin_kernel<<<NB, 256, 0, stream>>>(pairs, cursor, colBase, meta, col, N);

    const int nrb = (N + 127) / 128;

    // ---- layer 1: 128 -> 128
    gather_f8<128><<<(N + 15) / 16, 256, 0, stream>>>(xf8, meta, col, aggb, N);
    mfma_layer<128, 128, false, true><<<nrb * 1, 256, 0, stream>>>(
        xbf, aggb, w1lT, w1rT, b1, g1, be1, m1, v1, h1, h1f8, N);

    // ---- layer 2: 128 -> 256
    gather_f8<128><<<(N + 15) / 16, 256, 0, stream>>>(h1f8, meta, col, aggb, N);
    mfma_layer<128, 256, false, true><<<nrb * 2, 256, 0, stream>>>(
        h1, aggb, w2lT, w2rT, b2, g2, be2, m2, v2, h2, h2f8, N);

    // ---- layer 3: 256 -> 256
    gather_f8<256><<<(N + 7) / 8, 256, 0, stream>>>(h2f8, meta, col, aggb, N);
    mfma_layer<256, 256, true, false><<<nrb * 2, 256, 0, stream>>>(
        h2, aggb, w3lT, w3rT, b3, g3, be3, m3, v3, out, nullptr, N);
}